// Round 5
// baseline (1480.817 us; speedup 1.0000x reference)
//
#include <hip/hip_runtime.h>

typedef _Float16 half_t;
typedef _Float16 half8 __attribute__((ext_vector_type(8)));
typedef _Float16 h2 __attribute__((ext_vector_type(2)));
typedef float float2v __attribute__((ext_vector_type(2)));
typedef float float4v __attribute__((ext_vector_type(4)));
typedef unsigned uint4v __attribute__((ext_vector_type(4)));
typedef unsigned short us8 __attribute__((ext_vector_type(8)));

constexpr int NB = 64;    // batch
constexpr int NT = 50;    // steps
constexpr int NS = 256;   // state dim
constexpr int NA = 64;    // action dim
constexpr int NH = 256;   // hypernet hidden
constexpr int NG = 64;    // Chebyshev-Gauss nodes for tanh(z*w+b) interpolation

constexpr float LO_SCALE = 2048.0f;
constexpr float LO_INV   = 1.0f / 2048.0f;
constexpr float ZC = 1.0f;   // z = ctx + t/50 in [0, 1.98]
constexpr float ZR = 1.05f;  // interval [-0.05, 2.05]
constexpr float PI_F = 3.14159265358979323846f;

#if defined(__has_builtin)
#if __has_builtin(__builtin_amdgcn_fdot2)
#define HAVE_FDOT2 1
#endif
#endif

__device__ __forceinline__ float fdot2f(h2 a, h2 b, float c) {
#ifdef HAVE_FDOT2
  return __builtin_amdgcn_fdot2(a, b, c, false);
#else
  return c + (float)a[0] * (float)b[0] + (float)a[1] * (float)b[1];
#endif
}

__device__ __forceinline__ h2 as_h2(unsigned u) {
  union { unsigned u; h2 v; } X; X.u = u; return X.v;
}
__device__ __forceinline__ void split_hl(float v, unsigned short& hs, unsigned short& ls) {
  half_t hi = (half_t)v;
  half_t lo = (half_t)((v - (float)hi) * LO_SCALE);
  union { half_t h; unsigned short s; } A;
  A.h = hi; hs = A.s;
  A.h = lo; ls = A.s;
}

// ---------------- prep kernels ----------------

// Gt[h][g] = tanh(z_g*W1a[h]+b1a[h]); Gbt likewise for b-net
__global__ void k_g(const float* __restrict__ W1a, const float* __restrict__ b1a,
                    const float* __restrict__ W1b, const float* __restrict__ b1b,
                    float* __restrict__ Gt, float* __restrict__ Gbt) {
  int g = blockIdx.x, h = threadIdx.x;
  float th = PI_F * (float)(2 * g + 1) / (float)(2 * NG);
  float zg = ZC + ZR * cosf(th);
  Gt[h * NG + g]  = tanhf(zg * W1a[h] + b1a[h]);
  Gbt[h * NG + g] = tanhf(zg * W1b[h] + b1b[h]);
}

// barycentric Lagrange weights L_g(z_tb), f32 [tb][g]
__global__ void k_lag(const float* __restrict__ ctx, float* __restrict__ Lf) {
  int idx = blockIdx.x * 256 + threadIdx.x;
  if (idx >= NT * NB) return;
  int t = idx >> 6, b = idx & 63;
  float z = ctx[b] + (float)t / 50.0f;
  float q[NG];
  float den = 0.f;
  int hit = -1;
#pragma unroll
  for (int g = 0; g < NG; ++g) {
    float th = PI_F * (float)(2 * g + 1) / (float)(2 * NG);
    float zg = ZC + ZR * cosf(th);
    float d = z - zg;
    if (fabsf(d) < 1e-7f) hit = g;
    float lam = ((g & 1) ? -1.f : 1.f) * sinf(th);
    float qq = lam / d;
    q[g] = qq;
    den += qq;
  }
  float rden = 1.f / den;
#pragma unroll
  for (int g = 0; g < NG; ++g) {
    float L = (hit >= 0) ? ((g == hit) ? 1.f : 0.f) : q[g] * rden;
    Lf[(size_t)idx * NG + g] = L;
  }
}

// V[t][b][i] = b2b-row(i) . u[t,b]
__global__ void k_v(const float* __restrict__ b2b, const float* __restrict__ us,
                    float* __restrict__ V) {
  int tb = blockIdx.x;
  int t = tb / NB, b = tb % NB;
  int i = threadIdx.x;
  __shared__ float ush[NA];
  if (i < NA) ush[i] = us[((size_t)b * NT + t) * NA + i];
  __syncthreads();
  const float* row = b2b + (size_t)i * NA;
  float s = 0.f;
#pragma unroll 8
  for (int j = 0; j < NA; ++j) s += row[j] * ush[j];
  V[(size_t)tb * NS + i] = s;
}

// MGf[g][m] = sum_h Gt[h][g]*W2a[h][m], f32 (both read & write coalesced over m)
__launch_bounds__(256)
__global__ void k_mg(const float* __restrict__ W2a, const float* __restrict__ Gt,
                     float* __restrict__ MGf) {
  const int tid = threadIdx.x;
  const size_t m = (size_t)blockIdx.x * 256 + tid;
  float acc[NG];
#pragma unroll
  for (int g = 0; g < NG; ++g) acc[g] = 0.f;
  for (int h = 0; h < NH; ++h) {
    float w = W2a[(size_t)h * (NS * NS) + m];
    const float* gr = Gt + h * NG;   // uniform -> scalar loads
#pragma unroll
    for (int g = 0; g < NG; ++g) acc[g] += gr[g] * w;
  }
#pragma unroll
  for (int g = 0; g < NG; ++g) MGf[(size_t)g * (NS * NS) + m] = acc[g];
}

// MBt[ks][i][(g&3)*64+j] = sum_h Gbt[h][g]*W2b[h][i*64+j]  (ks = g>>2), hi/lo f16
__launch_bounds__(256)
__global__ void k_mb(const float* __restrict__ W2b, const float* __restrict__ Gbt,
                     unsigned short* __restrict__ MBTh, unsigned short* __restrict__ MBTl) {
  __shared__ unsigned short sh_[256 * 66];
  __shared__ unsigned short sl_[256 * 66];
  const int tid = threadIdx.x;
  const int m = blockIdx.x * 256 + tid;          // m = i*64 + j, 16384 total
  float acc[NG];
#pragma unroll
  for (int g = 0; g < NG; ++g) acc[g] = 0.f;
  for (int h = 0; h < NH; ++h) {
    float w = W2b[(size_t)h * (NS * NA) + m];
    const float* gr = Gbt + h * NG;
#pragma unroll
    for (int g = 0; g < NG; ++g) acc[g] += gr[g] * w;
  }
#pragma unroll
  for (int g = 0; g < NG; ++g) {
    unsigned short hs, ls;
    split_hl(acc[g], hs, ls);
    sh_[tid * 66 + g] = hs;
    sl_[tid * 66 + g] = ls;
  }
  __syncthreads();
  const int i0 = blockIdx.x * 4;                 // block covers 4 i-rows
  for (int it = 0; it < 64; ++it) {
    int flat = it * 256 + tid;                   // ii*4096 + K
    int ii = flat >> 12, K = flat & 4095;
    int g = K >> 6, j = K & 63;
    size_t dst = ((size_t)(K >> 8) * NS + (i0 + ii)) * 256 + (K & 255);
    MBTh[dst] = sh_[(ii * 64 + j) * 66 + g];
    MBTl[dst] = sl_[(ii * 64 + j) * 66 + g];
  }
}

// Upt[ks][tb][(g&3)*64+j] = L_g[tb]*u[tb][j]  (ks = g>>2), hi/lo f16
__global__ void k_up(const float* __restrict__ Lf, const float* __restrict__ usin,
                     unsigned short* __restrict__ Uph, unsigned short* __restrict__ Upl) {
  int tb = blockIdx.x, tid = threadIdx.x;
  int t = tb >> 6, b = tb & 63;
  __shared__ float Ls[64], uu[64];
  if (tid < 64) Ls[tid] = Lf[(size_t)tb * NG + tid];
  else if (tid < 128) uu[tid - 64] = usin[((size_t)b * NT + t) * NA + (tid - 64)];
  __syncthreads();
  int g = tid >> 2, jc = tid & 3;
  float Lg = Ls[g];
  us8 hv0, hv1, lv0, lv1;
#pragma unroll
  for (int k = 0; k < 8; ++k) {
    unsigned short hs, ls;
    split_hl(Lg * uu[jc * 16 + k], hs, ls);
    hv0[k] = hs; lv0[k] = ls;
  }
#pragma unroll
  for (int k = 0; k < 8; ++k) {
    unsigned short hs, ls;
    split_hl(Lg * uu[jc * 16 + 8 + k], hs, ls);
    hv1[k] = hs; lv1[k] = ls;
  }
  size_t ob = ((size_t)(g >> 2) * (NT * NB) + tb) * 256 + (g & 3) * 64 + jc * 16;
  *(us8*)(Uph + ob) = hv0; *(us8*)(Uph + ob + 8) = hv1;
  *(us8*)(Upl + ob) = lv0; *(us8*)(Upl + ob + 8) = lv1;
}

// x0 -> packed hi|lo state
__global__ void k_x0(const float* __restrict__ x0, unsigned* __restrict__ Xst) {
  int idx = blockIdx.x * 256 + threadIdx.x;
  float x = x0[idx];
  half_t hi = (half_t)x;
  half_t lo = (half_t)((x - (float)hi) * LO_SCALE);
  union { half_t h[2]; unsigned u; } P;
  P.h[0] = hi; P.h[1] = lo;
  Xst[idx] = P.u;
}

// Bu GEMM: V[tb][i] += sum_K Up[tb][K]*MBT[i][K]; slab-major, Ksplit=16.
// cf-loop blocked 4x4 so only 8 accumulators live at a time (anti-spill).
__launch_bounds__(256, 4)
__global__ void k_bu2(const unsigned short* __restrict__ Uph,
                      const unsigned short* __restrict__ Upl,
                      const unsigned short* __restrict__ MBTh,
                      const unsigned short* __restrict__ MBTl,
                      float* __restrict__ V) {
  const int tid = threadIdx.x;
  const int wv = tid >> 6, lane = tid & 63;
  const int l15 = lane & 15, quad = lane >> 4;
  const int mt = blockIdx.x >> 4, ks = blockIdx.x & 15;
  const int r0 = mt * 64 + wv * 16;
  half8 ah[8], al[8];
  const size_t ab = ((size_t)ks * (NT * NB) + r0 + l15) * 256 + quad * 8;
#pragma unroll
  for (int k8 = 0; k8 < 8; ++k8) {
    ah[k8] = *(const half8*)(Uph + ab + k8 * 32);
    al[k8] = *(const half8*)(Upl + ab + k8 * 32);
  }
  for (int cg = 0; cg < 4; ++cg) {
    float4v accA[4], accC[4];
#pragma unroll
    for (int c = 0; c < 4; ++c) {
      accA[c] = (float4v){0.f, 0.f, 0.f, 0.f};
      accC[c] = (float4v){0.f, 0.f, 0.f, 0.f};
    }
#pragma unroll
    for (int c = 0; c < 4; ++c) {
      const int cf = cg * 4 + c;
      const size_t bb = ((size_t)ks * NS + cf * 16 + l15) * 256 + quad * 8;
#pragma unroll
      for (int k8 = 0; k8 < 8; ++k8) {
        half8 bh = *(const half8*)(MBTh + bb + k8 * 32);
        half8 bl = *(const half8*)(MBTl + bb + k8 * 32);
        accA[c] = __builtin_amdgcn_mfma_f32_16x16x32_f16(ah[k8], bh, accA[c], 0, 0, 0);
        accC[c] = __builtin_amdgcn_mfma_f32_16x16x32_f16(ah[k8], bl, accC[c], 0, 0, 0);
        accC[c] = __builtin_amdgcn_mfma_f32_16x16x32_f16(al[k8], bh, accC[c], 0, 0, 0);
      }
    }
#pragma unroll
    for (int c = 0; c < 4; ++c) {
      const int cf = cg * 4 + c;
#pragma unroll
      for (int r = 0; r < 4; ++r) {
        int row = r0 + quad * 4 + r;
        atomicAdd(V + (size_t)row * NS + cf * 16 + l15,
                  accA[c][r] + accC[c][r] * LO_INV);
      }
    }
  }
}

// ---------------- fused pipeline kernel (1024 threads) ----------------
// blocks [0, nroll): rollout chains (16 waves per b) for chunk (t0r, tnr).
// blocks [nroll, nroll+128): direct-VALU A-materialization for chunk t0p,
//   each block covers 1024 m-columns x half the chunk rows.
__launch_bounds__(1024, 4)
__global__ void k_pr(const unsigned short* Arh, const unsigned short* Arl,
                     unsigned short* Awh, unsigned short* Awl,
                     const float* __restrict__ Lf,
                     const float* __restrict__ MGf,
                     const float* __restrict__ b2a, const float* __restrict__ V,
                     unsigned* __restrict__ Xst, float* __restrict__ out,
                     int nroll, int t0r, int tnr, int t0p, int tnp) {
  __shared__ __align__(16) float Lsh[160 * 64];   // 40 KiB
  const int tid = threadIdx.x;
  const int bid = blockIdx.x;

  if (bid < nroll) {
    // ===== rollout role: one block (16 waves) per batch chain =====
    __builtin_amdgcn_s_setprio(1);
    unsigned short* xb = (unsigned short*)Lsh;
    // layout: xh[c][i] = xb[c*256+i], xl[c][i] = xb[512 + c*256 + i]
    const int b = bid;
    const int wv = tid >> 6, lane = tid & 63;
    const int jg = lane & 15, ir = lane >> 4;
    const int i0 = wv * 16 + ir * 4;
    if (tid < 256) {
      unsigned pxx = Xst[b * 256 + tid];
      xb[tid] = (unsigned short)(pxx & 0xffffu);
      xb[512 + tid] = (unsigned short)(pxx >> 16);
    }
    __syncthreads();
    int cur = 0;
    for (int tt = 0; tt < tnr; ++tt) {
      const int t = t0r + tt;
      const size_t rb = ((size_t)tt * NB + b) * (NS * NS);
      uint4v xhv[2], xlv[2];
      xhv[0] = *(const uint4v*)(xb + cur * 256 + jg * 16);
      xhv[1] = *(const uint4v*)(xb + cur * 256 + jg * 16 + 8);
      xlv[0] = *(const uint4v*)(xb + 512 + cur * 256 + jg * 16);
      xlv[1] = *(const uint4v*)(xb + 512 + cur * 256 + jg * 16 + 8);
      float dt[4];
#pragma unroll
      for (int i = 0; i < 4; ++i) {
        const size_t ro = rb + (size_t)(i0 + i) * NS + jg * 16;
        uint4v a0 = *(const uint4v*)(Arh + ro);
        uint4v a1 = *(const uint4v*)(Arh + ro + 8);
        uint4v c0 = *(const uint4v*)(Arl + ro);
        uint4v c1 = *(const uint4v*)(Arl + ro + 8);
        float s1 = 0.f, s2 = 0.f;
#pragma unroll
        for (int p = 0; p < 4; ++p) {
          s1 = fdot2f(as_h2(a0[p]), as_h2(xhv[0][p]), s1);
          s2 = fdot2f(as_h2(a0[p]), as_h2(xlv[0][p]), s2);
          s2 = fdot2f(as_h2(c0[p]), as_h2(xhv[0][p]), s2);
          s1 = fdot2f(as_h2(a1[p]), as_h2(xhv[1][p]), s1);
          s2 = fdot2f(as_h2(a1[p]), as_h2(xlv[1][p]), s2);
          s2 = fdot2f(as_h2(c1[p]), as_h2(xhv[1][p]), s2);
        }
        dt[i] = s1 + s2 * LO_INV;
      }
#pragma unroll
      for (int s = 1; s < 16; s <<= 1)
#pragma unroll
        for (int i = 0; i < 4; ++i) dt[i] += __shfl_xor(dt[i], s);
      if (jg == 0) {
        float4v vv = *(const float4v*)(V + ((size_t)t * NB + b) * NS + i0);
        float4v xn;
#pragma unroll
        for (int r = 0; r < 4; ++r) xn[r] = dt[r] + vv[r];
        *(float4v*)(out + ((size_t)b * NT + t) * NS + i0) = xn;
#pragma unroll
        for (int r = 0; r < 4; ++r) {
          unsigned short hs, ls;
          split_hl(xn[r], hs, ls);
          xb[(cur ^ 1) * 256 + i0 + r] = hs;
          xb[512 + (cur ^ 1) * 256 + i0 + r] = ls;
        }
      }
      __syncthreads();
      cur ^= 1;
    }
    if (tid < 256) {
      unsigned pxx = (unsigned)xb[cur * 256 + tid] | ((unsigned)xb[512 + cur * 256 + tid] << 16);
      Xst[b * 256 + tid] = pxx;
    }
    __builtin_amdgcn_s_setprio(0);
  } else {
    // ===== direct A-materialization role (next chunk): pure f32 VALU =====
    const int pb = bid - nroll;
    const int rh = pb >> 6;                 // row half 0/1
    const int cb = (pb & 63) * 1024;        // m-column base (1024 cols/block)
    const int half = tnp * 32;              // rows per block (<=160)
    const int r0p = rh * half;
    const int nf = half * NG;               // floats of L to stage
    for (int f = tid * 4; f < nf; f += 4096)
      *(float4v*)(Lsh + f) =
          *(const float4v*)(Lf + ((size_t)(t0p * NB + r0p)) * NG + f);
    __syncthreads();
    const int m = cb + tid;
    float2v mg2[32];
#pragma unroll
    for (int g2 = 0; g2 < 32; ++g2) {
      mg2[g2][0] = MGf[(size_t)(g2 * 2) * (NS * NS) + m];
      mg2[g2][1] = MGf[(size_t)(g2 * 2 + 1) * (NS * NS) + m];
    }
    const float b2v = b2a[m];
    for (int r = 0; r < half; ++r) {
      const float4v* Lr = (const float4v*)(Lsh + r * NG);
      float2v a2 = {0.f, 0.f};
#pragma unroll
      for (int g4 = 0; g4 < 16; ++g4) {
        float4v L4 = Lr[g4];
        float2v l01 = {L4[0], L4[1]};
        float2v l23 = {L4[2], L4[3]};
        a2 += l01 * mg2[g4 * 2];
        a2 += l23 * mg2[g4 * 2 + 1];
      }
      float v = a2[0] + a2[1] + b2v;
      unsigned short hs, ls;
      split_hl(v, hs, ls);
      const size_t gb = (size_t)(r0p + r) * (NS * NS) + m;
      Awh[gb] = hs;
      Awl[gb] = ls;
    }
  }
}

// ---------------- launch ----------------

static inline int imin(int a, int b) { return a < b ? a : b; }

extern "C" void kernel_launch(void* const* d_in, const int* in_sizes, int n_in,
                              void* d_out, int out_size, void* d_ws, size_t ws_size,
                              hipStream_t stream) {
  const float* x0  = (const float*)d_in[0];
  const float* ctx = (const float*)d_in[1];
  const float* usin = (const float*)d_in[2];
  const float* W1a = (const float*)d_in[3];
  const float* b1a = (const float*)d_in[4];
  const float* W2a = (const float*)d_in[5];
  const float* b2a = (const float*)d_in[6];
  const float* W1b = (const float*)d_in[7];
  const float* b1b = (const float*)d_in[8];
  const float* W2b = (const float*)d_in[9];
  const float* b2b = (const float*)d_in[10];
  float* out = (float*)d_out;

  const size_t perT  = (size_t)NB * NS * NS * 2;     //  8,388,608 (one array, per t)
  const size_t szMGf = (size_t)NS * NS * NG * 4;     // 16,777,216
  const size_t szMBT = (size_t)NS * NG * NA * 2;     //  2,097,152 each
  const size_t szLf  = (size_t)NT * NB * NG * 4;     //    819,200
  const size_t szGt  = (size_t)NH * NG * 4;          //     65,536 each
  const size_t szUp1 = (size_t)NT * NB * NG * NA * 2;// 26,214,400 each
  const size_t szV   = (size_t)NT * NB * NS * 4;     //  3,276,800
  const size_t szXst = (size_t)NB * NS * 4;          //     65,536

  const size_t fixed = szMGf + 2 * szMBT + szLf + 2 * szGt + 2 * szUp1 + szV + szXst;

  size_t avail = (ws_size > fixed) ? (ws_size - fixed) : 0;
  bool dbuf = true;
  int Tc = (int)(avail / (4 * perT));
  if (Tc > 5) Tc = 5;   // LDS L-stage sized for tnp<=5; 168MB A-set fits L3
  if (Tc < 1) {
    dbuf = false;
    Tc = (int)(avail / (2 * perT));
    if (Tc > 5) Tc = 5;
    if (Tc < 1) Tc = 1;
  }

  char* p = (char*)d_ws;
  unsigned short* A0h = (unsigned short*)p; p += (size_t)Tc * perT;
  unsigned short* A0l = (unsigned short*)p; p += (size_t)Tc * perT;
  unsigned short* A1h = A0h; unsigned short* A1l = A0l;
  if (dbuf) {
    A1h = (unsigned short*)p; p += (size_t)Tc * perT;
    A1l = (unsigned short*)p; p += (size_t)Tc * perT;
  }
  float* MGf = (float*)p; p += szMGf;
  unsigned short* MBTh = (unsigned short*)p; p += szMBT;
  unsigned short* MBTl = (unsigned short*)p; p += szMBT;
  float* Lf  = (float*)p; p += szLf;
  float* Gt  = (float*)p; p += szGt;
  float* Gbt = (float*)p; p += szGt;
  unsigned short* Uph = (unsigned short*)p; p += szUp1;
  unsigned short* Upl = (unsigned short*)p; p += szUp1;
  float* Vg  = (float*)p; p += szV;
  unsigned* Xst = (unsigned*)p;

  // prep (all fully parallel)
  k_g<<<NG, NH, 0, stream>>>(W1a, b1a, W1b, b1b, Gt, Gbt);
  k_lag<<<(NT * NB + 255) / 256, 256, 0, stream>>>(ctx, Lf);
  k_v<<<NT * NB, NS, 0, stream>>>(b2b, usin, Vg);
  k_mg<<<NS * NS / 256, 256, 0, stream>>>(W2a, Gt, MGf);
  k_mb<<<NS * NA / 256, 256, 0, stream>>>(W2b, Gbt, MBTh, MBTl);
  k_up<<<NT * NB, 256, 0, stream>>>(Lf, usin, Uph, Upl);
  k_x0<<<NB, 256, 0, stream>>>(x0, Xst);
  k_bu2<<<(NT * NB / 64) * 16, 256, 0, stream>>>(Uph, Upl, MBTh, MBTl, Vg);

  (void)in_sizes; (void)n_in; (void)out_size;

  const int nc = (NT + Tc - 1) / Tc;
  if (dbuf) {
    // pipelined: launch L runs roll(chunk L-1) || pre(chunk L)
    for (int L = 0; L <= nc; ++L) {
      const int rc = L - 1, pc = L;
      const int nroll = (rc >= 0) ? NB : 0;
      const int t0r = (rc >= 0) ? rc * Tc : 0;
      const int tnr = (rc >= 0) ? imin(Tc, NT - t0r) : 0;
      const int t0p = (pc < nc) ? pc * Tc : 0;
      const int tnp = (pc < nc) ? imin(Tc, NT - t0p) : 0;
      const int grid = nroll + (tnp > 0 ? 128 : 0);
      const unsigned short* Arh = ((rc & 1) ? A1h : A0h);
      const unsigned short* Arl = ((rc & 1) ? A1l : A0l);
      unsigned short* Awh = ((pc & 1) ? A1h : A0h);
      unsigned short* Awl = ((pc & 1) ? A1l : A0l);
      k_pr<<<grid, 1024, 0, stream>>>(Arh, Arl, Awh, Awl, Lf, MGf,
                                      b2a, Vg, Xst, out, nroll, t0r, tnr, t0p, tnp);
    }
  } else {
    // sequential fallback on a single buffer
    for (int c = 0; c < nc; ++c) {
      const int t0 = c * Tc, tn = imin(Tc, NT - t0);
      k_pr<<<128, 1024, 0, stream>>>(A0h, A0l, A0h, A0l, Lf, MGf,
                                     b2a, Vg, Xst, out, 0, 0, 0, t0, tn);
      k_pr<<<NB, 1024, 0, stream>>>(A0h, A0l, A0h, A0l, Lf, MGf,
                                    b2a, Vg, Xst, out, NB, t0, tn, 0, 0);
    }
  }
}

// Round 6
// 1067.899 us; speedup vs baseline: 1.3867x; 1.3867x over previous
//
#include <hip/hip_runtime.h>

typedef _Float16 half_t;
typedef _Float16 half8 __attribute__((ext_vector_type(8)));
typedef _Float16 h2 __attribute__((ext_vector_type(2)));
typedef float float2v __attribute__((ext_vector_type(2)));
typedef float float4v __attribute__((ext_vector_type(4)));
typedef unsigned uint4v __attribute__((ext_vector_type(4)));
typedef unsigned short us8 __attribute__((ext_vector_type(8)));

constexpr int NB = 64;    // batch
constexpr int NT = 50;    // steps
constexpr int NS = 256;   // state dim
constexpr int NA = 64;    // action dim
constexpr int NH = 256;   // hypernet hidden
constexpr int NG = 64;    // Chebyshev-Gauss nodes

constexpr float LO_SCALE = 2048.0f;
constexpr float LO_INV   = 1.0f / 2048.0f;
constexpr float ZC = 1.0f;   // z = ctx + t/50 in [0, 1.98]
constexpr float ZR = 1.05f;  // interval [-0.05, 2.05]
constexpr float PI_F = 3.14159265358979323846f;

#if defined(__has_builtin)
#if __has_builtin(__builtin_amdgcn_fdot2)
#define HAVE_FDOT2 1
#endif
#endif

__device__ __forceinline__ float fdot2f(h2 a, h2 b, float c) {
#ifdef HAVE_FDOT2
  return __builtin_amdgcn_fdot2(a, b, c, false);
#else
  return c + (float)a[0] * (float)b[0] + (float)a[1] * (float)b[1];
#endif
}

__device__ __forceinline__ h2 as_h2(unsigned u) {
  union { unsigned u; h2 v; } X; X.u = u; return X.v;
}
__device__ __forceinline__ void split_hl(float v, unsigned short& hs, unsigned short& ls) {
  half_t hi = (half_t)v;
  half_t lo = (half_t)((v - (float)hi) * LO_SCALE);
  union { half_t h; unsigned short s; } A;
  A.h = hi; hs = A.s;
  A.h = lo; ls = A.s;
}

// ---------------- prep kernels ----------------

__global__ void k_g(const float* __restrict__ W1a, const float* __restrict__ b1a,
                    const float* __restrict__ W1b, const float* __restrict__ b1b,
                    float* __restrict__ Gt, float* __restrict__ Gbt) {
  int g = blockIdx.x, h = threadIdx.x;
  float th = PI_F * (float)(2 * g + 1) / (float)(2 * NG);
  float zg = ZC + ZR * cosf(th);
  Gt[h * NG + g]  = tanhf(zg * W1a[h] + b1a[h]);
  Gbt[h * NG + g] = tanhf(zg * W1b[h] + b1b[h]);
}

__global__ void k_lag(const float* __restrict__ ctx, float* __restrict__ Lf) {
  int idx = blockIdx.x * 256 + threadIdx.x;
  if (idx >= NT * NB) return;
  int t = idx >> 6, b = idx & 63;
  float z = ctx[b] + (float)t / 50.0f;
  float q[NG];
  float den = 0.f;
  int hit = -1;
#pragma unroll
  for (int g = 0; g < NG; ++g) {
    float th = PI_F * (float)(2 * g + 1) / (float)(2 * NG);
    float zg = ZC + ZR * cosf(th);
    float d = z - zg;
    if (fabsf(d) < 1e-7f) hit = g;
    float lam = ((g & 1) ? -1.f : 1.f) * sinf(th);
    float qq = lam / d;
    q[g] = qq;
    den += qq;
  }
  float rden = 1.f / den;
#pragma unroll
  for (int g = 0; g < NG; ++g) {
    float L = (hit >= 0) ? ((g == hit) ? 1.f : 0.f) : q[g] * rden;
    Lf[(size_t)idx * NG + g] = L;
  }
}

__global__ void k_v(const float* __restrict__ b2b, const float* __restrict__ us,
                    float* __restrict__ V) {
  int tb = blockIdx.x;
  int t = tb / NB, b = tb % NB;
  int i = threadIdx.x;
  __shared__ float ush[NA];
  if (i < NA) ush[i] = us[((size_t)b * NT + t) * NA + i];
  __syncthreads();
  const float* row = b2b + (size_t)i * NA;
  float s = 0.f;
#pragma unroll 8
  for (int j = 0; j < NA; ++j) s += row[j] * ush[j];
  V[(size_t)tb * NS + i] = s;
}

// --- MG two-stage (h-split x4 for occupancy) ---
// stage 1: Pp[(hq*NG+g)][m] = sum_{h in quarter} Gt[h][g]*W2a[h][m]
__launch_bounds__(256)
__global__ void k_mg1(const float* __restrict__ W2a, const float* __restrict__ Gt,
                      float* __restrict__ Pp) {
  const int tid = threadIdx.x;
  const int mb = blockIdx.x & 255, hq = blockIdx.x >> 8;
  const size_t m = (size_t)mb * 256 + tid;
  float acc[NG];
#pragma unroll
  for (int g = 0; g < NG; ++g) acc[g] = 0.f;
  const int h0 = hq * 64;
  for (int hh = 0; hh < 64; ++hh) {
    const int h = h0 + hh;
    float w = W2a[(size_t)h * (NS * NS) + m];
    const float* gr = Gt + h * NG;   // uniform -> scalar loads
#pragma unroll
    for (int g = 0; g < NG; ++g) acc[g] += gr[g] * w;
  }
#pragma unroll
  for (int g = 0; g < NG; ++g)
    Pp[(size_t)(hq * NG + g) * (NS * NS) + m] = acc[g];
}
// stage 2: MGf[g][m] = sum_hq Pp
__global__ void k_mg2(const float* __restrict__ Pp, float* __restrict__ MGf) {
  const size_t i4 = ((size_t)blockIdx.x * 256 + threadIdx.x) * 4;
  const size_t Q = (size_t)NG * NS * NS;     // 4,194,304
  float4v s = *(const float4v*)(Pp + i4);
  s += *(const float4v*)(Pp + Q + i4);
  s += *(const float4v*)(Pp + 2 * Q + i4);
  s += *(const float4v*)(Pp + 3 * Q + i4);
  *(float4v*)(MGf + i4) = s;
}
// slow single-stage fallback (small-workspace path)
__launch_bounds__(256)
__global__ void k_mgS(const float* __restrict__ W2a, const float* __restrict__ Gt,
                      float* __restrict__ MGf) {
  const int tid = threadIdx.x;
  const size_t m = (size_t)blockIdx.x * 256 + tid;
  float acc[NG];
#pragma unroll
  for (int g = 0; g < NG; ++g) acc[g] = 0.f;
  for (int h = 0; h < NH; ++h) {
    float w = W2a[(size_t)h * (NS * NS) + m];
    const float* gr = Gt + h * NG;
#pragma unroll
    for (int g = 0; g < NG; ++g) acc[g] += gr[g] * w;
  }
#pragma unroll
  for (int g = 0; g < NG; ++g) MGf[(size_t)g * (NS * NS) + m] = acc[g];
}

// --- MB two-stage ---
// stage 1: Pb[(hq*NG+g)][m16k] partial sums
__launch_bounds__(256)
__global__ void k_mb1(const float* __restrict__ W2b, const float* __restrict__ Gbt,
                      float* __restrict__ Pb) {
  const int tid = threadIdx.x;
  const int mb = blockIdx.x & 63, hq = blockIdx.x >> 6;
  const int m = mb * 256 + tid;
  float acc[NG];
#pragma unroll
  for (int g = 0; g < NG; ++g) acc[g] = 0.f;
  const int h0 = hq * 64;
  for (int hh = 0; hh < 64; ++hh) {
    const int h = h0 + hh;
    float w = W2b[(size_t)h * (NS * NA) + m];
    const float* gr = Gbt + h * NG;
#pragma unroll
    for (int g = 0; g < NG; ++g) acc[g] += gr[g] * w;
  }
#pragma unroll
  for (int g = 0; g < NG; ++g)
    Pb[(size_t)(hq * NG + g) * (NS * NA) + m] = acc[g];
}
// stage 2: sum partials, split hi/lo, write slab-major MBT layout
__global__ void k_mb2(const float* __restrict__ Pb,
                      unsigned short* __restrict__ MBTh,
                      unsigned short* __restrict__ MBTl) {
  const int g = blockIdx.x & 63, mb = blockIdx.x >> 6;
  const int m = mb * 256 + threadIdx.x;          // m = i*64 + j
  const size_t Q = (size_t)NG * NS * NA;         // 1,048,576
  float s = Pb[(size_t)g * (NS * NA) + m];
  s += Pb[Q + (size_t)g * (NS * NA) + m];
  s += Pb[2 * Q + (size_t)g * (NS * NA) + m];
  s += Pb[3 * Q + (size_t)g * (NS * NA) + m];
  unsigned short hs, ls;
  split_hl(s, hs, ls);
  const int i = m >> 6, j = m & 63;
  const size_t dst = ((size_t)(g >> 2) * NS + i) * 256 + (g & 3) * 64 + j;
  MBTh[dst] = hs;
  MBTl[dst] = ls;
}
// slow fallback
__launch_bounds__(256)
__global__ void k_mbS(const float* __restrict__ W2b, const float* __restrict__ Gbt,
                      unsigned short* __restrict__ MBTh, unsigned short* __restrict__ MBTl) {
  const int tid = threadIdx.x;
  const int m = blockIdx.x * 256 + tid;
  float acc[NG];
#pragma unroll
  for (int g = 0; g < NG; ++g) acc[g] = 0.f;
  for (int h = 0; h < NH; ++h) {
    float w = W2b[(size_t)h * (NS * NA) + m];
    const float* gr = Gbt + h * NG;
#pragma unroll
    for (int g = 0; g < NG; ++g) acc[g] += gr[g] * w;
  }
  const int i = m >> 6, j = m & 63;
#pragma unroll
  for (int g = 0; g < NG; ++g) {
    unsigned short hs, ls;
    split_hl(acc[g], hs, ls);
    const size_t dst = ((size_t)(g >> 2) * NS + i) * 256 + (g & 3) * 64 + j;
    MBTh[dst] = hs;
    MBTl[dst] = ls;
  }
}

// Upt[ks][tb][(g&3)*64+j] = L_g[tb]*u[tb][j]  (ks = g>>2), hi/lo f16
__global__ void k_up(const float* __restrict__ Lf, const float* __restrict__ usin,
                     unsigned short* __restrict__ Uph, unsigned short* __restrict__ Upl) {
  int tb = blockIdx.x, tid = threadIdx.x;
  int t = tb >> 6, b = tb & 63;
  __shared__ float Ls[64], uu[64];
  if (tid < 64) Ls[tid] = Lf[(size_t)tb * NG + tid];
  else if (tid < 128) uu[tid - 64] = usin[((size_t)b * NT + t) * NA + (tid - 64)];
  __syncthreads();
  int g = tid >> 2, jc = tid & 3;
  float Lg = Ls[g];
  us8 hv0, hv1, lv0, lv1;
#pragma unroll
  for (int k = 0; k < 8; ++k) {
    unsigned short hs, ls;
    split_hl(Lg * uu[jc * 16 + k], hs, ls);
    hv0[k] = hs; lv0[k] = ls;
  }
#pragma unroll
  for (int k = 0; k < 8; ++k) {
    unsigned short hs, ls;
    split_hl(Lg * uu[jc * 16 + 8 + k], hs, ls);
    hv1[k] = hs; lv1[k] = ls;
  }
  size_t ob = ((size_t)(g >> 2) * (NT * NB) + tb) * 256 + (g & 3) * 64 + jc * 16;
  *(us8*)(Uph + ob) = hv0; *(us8*)(Uph + ob + 8) = hv1;
  *(us8*)(Upl + ob) = lv0; *(us8*)(Upl + ob + 8) = lv1;
}

// x0 -> packed hi|lo state
__global__ void k_x0(const float* __restrict__ x0, unsigned* __restrict__ Xst) {
  int idx = blockIdx.x * 256 + threadIdx.x;
  float x = x0[idx];
  half_t hi = (half_t)x;
  half_t lo = (half_t)((x - (float)hi) * LO_SCALE);
  union { half_t h[2]; unsigned u; } P;
  P.h[0] = hi; P.h[1] = lo;
  Xst[idx] = P.u;
}

// Bu GEMM: V[tb][i] += sum_K Up[tb][K]*MBT[i][K]; slab-major, Ksplit=16,
// cf-loop blocked 4x4 (anti-spill).
__launch_bounds__(256, 4)
__global__ void k_bu2(const unsigned short* __restrict__ Uph,
                      const unsigned short* __restrict__ Upl,
                      const unsigned short* __restrict__ MBTh,
                      const unsigned short* __restrict__ MBTl,
                      float* __restrict__ V) {
  const int tid = threadIdx.x;
  const int wv = tid >> 6, lane = tid & 63;
  const int l15 = lane & 15, quad = lane >> 4;
  const int mt = blockIdx.x >> 4, ks = blockIdx.x & 15;
  const int r0 = mt * 64 + wv * 16;
  half8 ah[8], al[8];
  const size_t ab = ((size_t)ks * (NT * NB) + r0 + l15) * 256 + quad * 8;
#pragma unroll
  for (int k8 = 0; k8 < 8; ++k8) {
    ah[k8] = *(const half8*)(Uph + ab + k8 * 32);
    al[k8] = *(const half8*)(Upl + ab + k8 * 32);
  }
  for (int cg = 0; cg < 4; ++cg) {
    float4v accA[4], accC[4];
#pragma unroll
    for (int c = 0; c < 4; ++c) {
      accA[c] = (float4v){0.f, 0.f, 0.f, 0.f};
      accC[c] = (float4v){0.f, 0.f, 0.f, 0.f};
    }
#pragma unroll
    for (int c = 0; c < 4; ++c) {
      const int cf = cg * 4 + c;
      const size_t bb = ((size_t)ks * NS + cf * 16 + l15) * 256 + quad * 8;
#pragma unroll
      for (int k8 = 0; k8 < 8; ++k8) {
        half8 bh = *(const half8*)(MBTh + bb + k8 * 32);
        half8 bl = *(const half8*)(MBTl + bb + k8 * 32);
        accA[c] = __builtin_amdgcn_mfma_f32_16x16x32_f16(ah[k8], bh, accA[c], 0, 0, 0);
        accC[c] = __builtin_amdgcn_mfma_f32_16x16x32_f16(ah[k8], bl, accC[c], 0, 0, 0);
        accC[c] = __builtin_amdgcn_mfma_f32_16x16x32_f16(al[k8], bh, accC[c], 0, 0, 0);
      }
    }
#pragma unroll
    for (int c = 0; c < 4; ++c) {
      const int cf = cg * 4 + c;
#pragma unroll
      for (int r = 0; r < 4; ++r) {
        int row = r0 + quad * 4 + r;
        atomicAdd(V + (size_t)row * NS + cf * 16 + l15,
                  accA[c][r] + accC[c][r] * LO_INV);
      }
    }
  }
}

// ---------------- fused pipeline kernel (1024 thr, 1 block/CU) ----------------
// blocks [0, nroll): rollout chains (16 waves, thread = (i, j-quarter)).
// blocks [nroll, nroll+192): pre role = 64 col-blocks x 3 row-thirds,
//   thread-per-column direct f32 VALU A-materialization.
__launch_bounds__(1024, 4)
__global__ void k_pr(const unsigned short* Arh, const unsigned short* Arl,
                     unsigned short* Awh, unsigned short* Awl,
                     const float* __restrict__ Lf,
                     const float* __restrict__ MGf,
                     const float* __restrict__ b2a, const float* __restrict__ V,
                     unsigned* __restrict__ Xst, float* __restrict__ out,
                     int nroll, int t0r, int tnr, int t0p, int tnp) {
  __shared__ __align__(16) float Lsh[6848];   // 26.75 KiB (107 rows x 64 g)
  const int tid = threadIdx.x;
  const int bid = blockIdx.x;

  if (bid < nroll) {
    // ===== rollout role =====
    __builtin_amdgcn_s_setprio(1);
    unsigned short* xb = (unsigned short*)Lsh;  // xh: [cur*256+i], xl: [512+cur*256+i]
    const int b = bid;
    const int i = tid >> 2, jq = tid & 3;
    if (tid < 256) {
      unsigned pxx = Xst[b * 256 + tid];
      xb[tid] = (unsigned short)(pxx & 0xffffu);
      xb[512 + tid] = (unsigned short)(pxx >> 16);
    }
    __syncthreads();
    int cur = 0;
    for (int tt = 0; tt < tnr; ++tt) {
      const int t = t0r + tt;
      const size_t ro = ((size_t)tt * NB + b) * (NS * NS) + (size_t)i * NS + jq * 64;
      const unsigned short* xhp = xb + cur * 256 + jq * 64;
      const unsigned short* xlp = xb + 512 + cur * 256 + jq * 64;
      float s1 = 0.f, s2 = 0.f;
#pragma unroll
      for (int q = 0; q < 8; ++q) {
        uint4v a4 = *(const uint4v*)(Arh + ro + q * 8);
        uint4v c4 = *(const uint4v*)(Arl + ro + q * 8);
        uint4v xh4 = *(const uint4v*)(xhp + q * 8);
        uint4v xl4 = *(const uint4v*)(xlp + q * 8);
#pragma unroll
        for (int p = 0; p < 4; ++p) {
          s1 = fdot2f(as_h2(a4[p]), as_h2(xh4[p]), s1);
          s2 = fdot2f(as_h2(a4[p]), as_h2(xl4[p]), s2);
          s2 = fdot2f(as_h2(c4[p]), as_h2(xh4[p]), s2);
        }
      }
      float d = s1 + s2 * LO_INV;
      d += __shfl_xor(d, 1);
      d += __shfl_xor(d, 2);
      if (jq == 0) {
        float xn = d + V[((size_t)t * NB + b) * NS + i];
        out[((size_t)b * NT + t) * NS + i] = xn;
        unsigned short hs, ls;
        split_hl(xn, hs, ls);
        xb[(cur ^ 1) * 256 + i] = hs;
        xb[512 + (cur ^ 1) * 256 + i] = ls;
      }
      __syncthreads();
      cur ^= 1;
    }
    if (tid < 256) {
      unsigned pxx = (unsigned)xb[cur * 256 + tid] |
                     ((unsigned)xb[512 + cur * 256 + tid] << 16);
      Xst[b * 256 + tid] = pxx;
    }
    __builtin_amdgcn_s_setprio(0);
  } else {
    // ===== pre role: direct f32 VALU A-materialization (next chunk) =====
    const int pb = bid - nroll;          // 0..191
    const int cbk = pb / 3, rth = pb % 3;
    const int m = cbk * 1024 + tid;      // this thread's output column
    const int R = tnp * NB;              // chunk rows (<=320)
    const int per = (R + 2) / 3;
    const int r0 = rth * per;
    const int r1 = (r0 + per < R) ? (r0 + per) : R;
    const int nf = (r1 - r0) * NG;
    for (int f = tid * 4; f < nf; f += 4096)
      *(float4v*)(Lsh + f) =
          *(const float4v*)(Lf + ((size_t)(t0p * NB + r0)) * NG + f);
    __syncthreads();
    float2v mg2[32];
#pragma unroll
    for (int g2 = 0; g2 < 32; ++g2) {
      mg2[g2][0] = MGf[(size_t)(g2 * 2) * (NS * NS) + m];
      mg2[g2][1] = MGf[(size_t)(g2 * 2 + 1) * (NS * NS) + m];
    }
    const float b2v = b2a[m];
    for (int r = r0; r < r1; ++r) {
      const float4v* Lr = (const float4v*)(Lsh + (r - r0) * NG);
      float2v a2 = {0.f, 0.f};
#pragma unroll
      for (int g4 = 0; g4 < 16; ++g4) {
        float4v L4 = Lr[g4];
        float2v l01 = {L4[0], L4[1]};
        float2v l23 = {L4[2], L4[3]};
        a2 += l01 * mg2[g4 * 2];
        a2 += l23 * mg2[g4 * 2 + 1];
      }
      float v = a2[0] + a2[1] + b2v;
      unsigned short hs, ls;
      split_hl(v, hs, ls);
      const size_t gb = (size_t)r * (NS * NS) + m;
      Awh[gb] = hs;
      Awl[gb] = ls;
    }
  }
}

// ---------------- launch ----------------

static inline int imin(int a, int b) { return a < b ? a : b; }

extern "C" void kernel_launch(void* const* d_in, const int* in_sizes, int n_in,
                              void* d_out, int out_size, void* d_ws, size_t ws_size,
                              hipStream_t stream) {
  const float* x0  = (const float*)d_in[0];
  const float* ctx = (const float*)d_in[1];
  const float* usin = (const float*)d_in[2];
  const float* W1a = (const float*)d_in[3];
  const float* b1a = (const float*)d_in[4];
  const float* W2a = (const float*)d_in[5];
  const float* b2a = (const float*)d_in[6];
  const float* W1b = (const float*)d_in[7];
  const float* b1b = (const float*)d_in[8];
  const float* W2b = (const float*)d_in[9];
  const float* b2b = (const float*)d_in[10];
  float* out = (float*)d_out;

  const size_t perT  = (size_t)NB * NS * NS * 2;     //  8,388,608 per t per array
  const size_t szMGf = (size_t)NS * NS * NG * 4;     // 16,777,216
  const size_t szMBT = (size_t)NS * NG * NA * 2;     //  2,097,152 each
  const size_t szLf  = (size_t)NT * NB * NG * 4;     //    819,200
  const size_t szGt  = (size_t)NH * NG * 4;          //     65,536 each
  const size_t szUp1 = (size_t)NT * NB * NG * NA * 2;// 26,214,400 each
  const size_t szV   = (size_t)NT * NB * NS * 4;     //  3,276,800
  const size_t szXst = (size_t)NB * NS * 4;          //     65,536
  const size_t szPp  = (size_t)NG * NS * NS * 4 * 4; // 67,108,864 (aliases A0)
  const size_t szPb  = (size_t)NG * NS * NA * 4 * 4; // 16,777,216 (aliases A0 tail)

  const size_t fixed = szMGf + 2 * szMBT + szLf + 2 * szGt + 2 * szUp1 + szV + szXst;

  size_t avail = (ws_size > fixed) ? (ws_size - fixed) : 0;
  bool dbuf = true;
  int Tc = (int)(avail / (4 * perT));
  if (Tc > 5) Tc = 5;   // pre LDS tile sized for tnp<=5
  if (Tc < 1) {
    dbuf = false;
    Tc = (int)(avail / (2 * perT));
    if (Tc > 5) Tc = 5;
    if (Tc < 1) Tc = 1;
  }

  char* p = (char*)d_ws;
  unsigned short* A0h = (unsigned short*)p; p += (size_t)Tc * perT;
  unsigned short* A0l = (unsigned short*)p; p += (size_t)Tc * perT;
  unsigned short* A1h = A0h; unsigned short* A1l = A0l;
  if (dbuf) {
    A1h = (unsigned short*)p; p += (size_t)Tc * perT;
    A1l = (unsigned short*)p; p += (size_t)Tc * perT;
  }
  float* MGf = (float*)p; p += szMGf;
  unsigned short* MBTh = (unsigned short*)p; p += szMBT;
  unsigned short* MBTl = (unsigned short*)p; p += szMBT;
  float* Lf  = (float*)p; p += szLf;
  float* Gt  = (float*)p; p += szGt;
  float* Gbt = (float*)p; p += szGt;
  unsigned short* Uph = (unsigned short*)p; p += szUp1;
  unsigned short* Upl = (unsigned short*)p; p += szUp1;
  float* Vg  = (float*)p; p += szV;
  unsigned* Xst = (unsigned*)p;

  // partial-sum scratch aliases the A buffers (used strictly before first k_pr)
  const bool fast_red = (2 * (size_t)Tc * perT) >= (szPp + szPb);
  float* Pp = (float*)A0h;
  float* Pb = Pp + szPp / 4;

  k_g<<<NG, NH, 0, stream>>>(W1a, b1a, W1b, b1b, Gt, Gbt);
  k_lag<<<(NT * NB + 255) / 256, 256, 0, stream>>>(ctx, Lf);
  k_v<<<NT * NB, NS, 0, stream>>>(b2b, usin, Vg);
  if (fast_red) {
    k_mg1<<<1024, 256, 0, stream>>>(W2a, Gt, Pp);
    k_mg2<<<(NG * NS * NS) / 1024, 256, 0, stream>>>(Pp, MGf);
    k_mb1<<<256, 256, 0, stream>>>(W2b, Gbt, Pb);
    k_mb2<<<64 * 64, 256, 0, stream>>>(Pb, MBTh, MBTl);
  } else {
    k_mgS<<<NS * NS / 256, 256, 0, stream>>>(W2a, Gt, MGf);
    k_mbS<<<NS * NA / 256, 256, 0, stream>>>(W2b, Gbt, MBTh, MBTl);
  }
  k_up<<<NT * NB, 256, 0, stream>>>(Lf, usin, Uph, Upl);
  k_x0<<<NB, 256, 0, stream>>>(x0, Xst);
  k_bu2<<<(NT * NB / 64) * 16, 256, 0, stream>>>(Uph, Upl, MBTh, MBTl, Vg);

  (void)in_sizes; (void)n_in; (void)out_size;

  const int nc = (NT + Tc - 1) / Tc;
  if (dbuf) {
    // pipelined: launch L runs roll(chunk L-1) || pre(chunk L); 64+192=256 blocks
    for (int L = 0; L <= nc; ++L) {
      const int rc = L - 1, pc = L;
      const int nroll = (rc >= 0) ? NB : 0;
      const int t0r = (rc >= 0) ? rc * Tc : 0;
      const int tnr = (rc >= 0) ? imin(Tc, NT - t0r) : 0;
      const int t0p = (pc < nc) ? pc * Tc : 0;
      const int tnp = (pc < nc) ? imin(Tc, NT - t0p) : 0;
      const int grid = nroll + (tnp > 0 ? 192 : 0);
      const unsigned short* Arh = ((rc & 1) ? A1h : A0h);
      const unsigned short* Arl = ((rc & 1) ? A1l : A0l);
      unsigned short* Awh = ((pc & 1) ? A1h : A0h);
      unsigned short* Awl = ((pc & 1) ? A1l : A0l);
      k_pr<<<grid, 1024, 0, stream>>>(Arh, Arl, Awh, Awl, Lf, MGf,
                                      b2a, Vg, Xst, out, nroll, t0r, tnr, t0p, tnp);
    }
  } else {
    // sequential fallback on a single buffer
    for (int c = 0; c < nc; ++c) {
      const int t0 = c * Tc, tn = imin(Tc, NT - t0);
      k_pr<<<192, 1024, 0, stream>>>(A0h, A0l, A0h, A0l, Lf, MGf,
                                     b2a, Vg, Xst, out, 0, 0, 0, t0, tn);
      k_pr<<<NB, 1024, 0, stream>>>(A0h, A0l, A0h, A0l, Lf, MGf,
                                    b2a, Vg, Xst, out, NB, t0, tn, 0, 0);
    }
  }
}

// Round 7
// 984.200 us; speedup vs baseline: 1.5046x; 1.0850x over previous
//
#include <hip/hip_runtime.h>

typedef _Float16 half_t;
typedef _Float16 half8 __attribute__((ext_vector_type(8)));
typedef _Float16 h2 __attribute__((ext_vector_type(2)));
typedef float float2v __attribute__((ext_vector_type(2)));
typedef float float4v __attribute__((ext_vector_type(4)));
typedef unsigned uint4v __attribute__((ext_vector_type(4)));
typedef unsigned short us8 __attribute__((ext_vector_type(8)));

constexpr int NB = 64;    // batch
constexpr int NT = 50;    // steps
constexpr int NS = 256;   // state dim
constexpr int NA = 64;    // action dim
constexpr int NH = 256;   // hypernet hidden
constexpr int NG = 64;    // Chebyshev-Gauss nodes

constexpr float LO_SCALE = 2048.0f;
constexpr float LO_INV   = 1.0f / 2048.0f;
constexpr float ZC = 1.0f;   // z = ctx + t/50 in [0, 1.98]
constexpr float ZR = 1.05f;  // interval [-0.05, 2.05]
constexpr float PI_F = 3.14159265358979323846f;

#if defined(__has_builtin)
#if __has_builtin(__builtin_amdgcn_fdot2)
#define HAVE_FDOT2 1
#endif
#endif

__device__ __forceinline__ float fdot2f(h2 a, h2 b, float c) {
#ifdef HAVE_FDOT2
  return __builtin_amdgcn_fdot2(a, b, c, false);
#else
  return c + (float)a[0] * (float)b[0] + (float)a[1] * (float)b[1];
#endif
}

__device__ __forceinline__ h2 as_h2(unsigned u) {
  union { unsigned u; h2 v; } X; X.u = u; return X.v;
}
__device__ __forceinline__ void split_hl(float v, unsigned short& hs, unsigned short& ls) {
  half_t hi = (half_t)v;
  half_t lo = (half_t)((v - (float)hi) * LO_SCALE);
  union { half_t h; unsigned short s; } A;
  A.h = hi; hs = A.s;
  A.h = lo; ls = A.s;
}

// ---------------- prep kernels ----------------

__global__ void k_g(const float* __restrict__ W1a, const float* __restrict__ b1a,
                    const float* __restrict__ W1b, const float* __restrict__ b1b,
                    float* __restrict__ Gt, float* __restrict__ Gbt) {
  int g = blockIdx.x, h = threadIdx.x;
  float th = PI_F * (float)(2 * g + 1) / (float)(2 * NG);
  float zg = ZC + ZR * cosf(th);
  Gt[h * NG + g]  = tanhf(zg * W1a[h] + b1a[h]);
  Gbt[h * NG + g] = tanhf(zg * W1b[h] + b1b[h]);
}

__global__ void k_lag(const float* __restrict__ ctx, float* __restrict__ Lf) {
  int idx = blockIdx.x * 256 + threadIdx.x;
  if (idx >= NT * NB) return;
  int t = idx >> 6, b = idx & 63;
  float z = ctx[b] + (float)t / 50.0f;
  float q[NG];
  float den = 0.f;
  int hit = -1;
#pragma unroll
  for (int g = 0; g < NG; ++g) {
    float th = PI_F * (float)(2 * g + 1) / (float)(2 * NG);
    float zg = ZC + ZR * cosf(th);
    float d = z - zg;
    if (fabsf(d) < 1e-7f) hit = g;
    float lam = ((g & 1) ? -1.f : 1.f) * sinf(th);
    float qq = lam / d;
    q[g] = qq;
    den += qq;
  }
  float rden = 1.f / den;
#pragma unroll
  for (int g = 0; g < NG; ++g) {
    float L = (hit >= 0) ? ((g == hit) ? 1.f : 0.f) : q[g] * rden;
    Lf[(size_t)idx * NG + g] = L;
  }
}

__global__ void k_v(const float* __restrict__ b2b, const float* __restrict__ us,
                    float* __restrict__ V) {
  int tb = blockIdx.x;
  int t = tb / NB, b = tb % NB;
  int i = threadIdx.x;
  __shared__ float ush[NA];
  if (i < NA) ush[i] = us[((size_t)b * NT + t) * NA + i];
  __syncthreads();
  const float* row = b2b + (size_t)i * NA;
  float s = 0.f;
#pragma unroll 8
  for (int j = 0; j < NA; ++j) s += row[j] * ush[j];
  V[(size_t)tb * NS + i] = s;
}

// --- MG two-stage (h-split x4 for occupancy) ---
__launch_bounds__(256)
__global__ void k_mg1(const float* __restrict__ W2a, const float* __restrict__ Gt,
                      float* __restrict__ Pp) {
  const int tid = threadIdx.x;
  const int mb = blockIdx.x & 255, hq = blockIdx.x >> 8;
  const size_t m = (size_t)mb * 256 + tid;
  float acc[NG];
#pragma unroll
  for (int g = 0; g < NG; ++g) acc[g] = 0.f;
  const int h0 = hq * 64;
  for (int hh = 0; hh < 64; ++hh) {
    const int h = h0 + hh;
    float w = W2a[(size_t)h * (NS * NS) + m];
    const float* gr = Gt + h * NG;
#pragma unroll
    for (int g = 0; g < NG; ++g) acc[g] += gr[g] * w;
  }
#pragma unroll
  for (int g = 0; g < NG; ++g)
    Pp[(size_t)(hq * NG + g) * (NS * NS) + m] = acc[g];
}
__global__ void k_mg2(const float* __restrict__ Pp, float* __restrict__ MGf) {
  const size_t i4 = ((size_t)blockIdx.x * 256 + threadIdx.x) * 4;
  const size_t Q = (size_t)NG * NS * NS;
  float4v s = *(const float4v*)(Pp + i4);
  s += *(const float4v*)(Pp + Q + i4);
  s += *(const float4v*)(Pp + 2 * Q + i4);
  s += *(const float4v*)(Pp + 3 * Q + i4);
  *(float4v*)(MGf + i4) = s;
}
__launch_bounds__(256)
__global__ void k_mgS(const float* __restrict__ W2a, const float* __restrict__ Gt,
                      float* __restrict__ MGf) {
  const int tid = threadIdx.x;
  const size_t m = (size_t)blockIdx.x * 256 + tid;
  float acc[NG];
#pragma unroll
  for (int g = 0; g < NG; ++g) acc[g] = 0.f;
  for (int h = 0; h < NH; ++h) {
    float w = W2a[(size_t)h * (NS * NS) + m];
    const float* gr = Gt + h * NG;
#pragma unroll
    for (int g = 0; g < NG; ++g) acc[g] += gr[g] * w;
  }
#pragma unroll
  for (int g = 0; g < NG; ++g) MGf[(size_t)g * (NS * NS) + m] = acc[g];
}

// --- MB two-stage ---
__launch_bounds__(256)
__global__ void k_mb1(const float* __restrict__ W2b, const float* __restrict__ Gbt,
                      float* __restrict__ Pb) {
  const int tid = threadIdx.x;
  const int mb = blockIdx.x & 63, hq = blockIdx.x >> 6;
  const int m = mb * 256 + tid;
  float acc[NG];
#pragma unroll
  for (int g = 0; g < NG; ++g) acc[g] = 0.f;
  const int h0 = hq * 64;
  for (int hh = 0; hh < 64; ++hh) {
    const int h = h0 + hh;
    float w = W2b[(size_t)h * (NS * NA) + m];
    const float* gr = Gbt + h * NG;
#pragma unroll
    for (int g = 0; g < NG; ++g) acc[g] += gr[g] * w;
  }
#pragma unroll
  for (int g = 0; g < NG; ++g)
    Pb[(size_t)(hq * NG + g) * (NS * NA) + m] = acc[g];
}
__global__ void k_mb2(const float* __restrict__ Pb,
                      unsigned short* __restrict__ MBTh,
                      unsigned short* __restrict__ MBTl) {
  const int g = blockIdx.x & 63, mb = blockIdx.x >> 6;
  const int m = mb * 256 + threadIdx.x;
  const size_t Q = (size_t)NG * NS * NA;
  float s = Pb[(size_t)g * (NS * NA) + m];
  s += Pb[Q + (size_t)g * (NS * NA) + m];
  s += Pb[2 * Q + (size_t)g * (NS * NA) + m];
  s += Pb[3 * Q + (size_t)g * (NS * NA) + m];
  unsigned short hs, ls;
  split_hl(s, hs, ls);
  const int i = m >> 6, j = m & 63;
  const size_t dst = ((size_t)(g >> 2) * NS + i) * 256 + (g & 3) * 64 + j;
  MBTh[dst] = hs;
  MBTl[dst] = ls;
}
__launch_bounds__(256)
__global__ void k_mbS(const float* __restrict__ W2b, const float* __restrict__ Gbt,
                      unsigned short* __restrict__ MBTh, unsigned short* __restrict__ MBTl) {
  const int tid = threadIdx.x;
  const int m = blockIdx.x * 256 + tid;
  float acc[NG];
#pragma unroll
  for (int g = 0; g < NG; ++g) acc[g] = 0.f;
  for (int h = 0; h < NH; ++h) {
    float w = W2b[(size_t)h * (NS * NA) + m];
    const float* gr = Gbt + h * NG;
#pragma unroll
    for (int g = 0; g < NG; ++g) acc[g] += gr[g] * w;
  }
  const int i = m >> 6, j = m & 63;
#pragma unroll
  for (int g = 0; g < NG; ++g) {
    unsigned short hs, ls;
    split_hl(acc[g], hs, ls);
    const size_t dst = ((size_t)(g >> 2) * NS + i) * 256 + (g & 3) * 64 + j;
    MBTh[dst] = hs;
    MBTl[dst] = ls;
  }
}

// Upt[ks][tb][(g&3)*64+j] = L_g[tb]*u[tb][j]  (ks = g>>2), hi/lo f16
__global__ void k_up(const float* __restrict__ Lf, const float* __restrict__ usin,
                     unsigned short* __restrict__ Uph, unsigned short* __restrict__ Upl) {
  int tb = blockIdx.x, tid = threadIdx.x;
  int t = tb >> 6, b = tb & 63;
  __shared__ float Ls[64], uu[64];
  if (tid < 64) Ls[tid] = Lf[(size_t)tb * NG + tid];
  else if (tid < 128) uu[tid - 64] = usin[((size_t)b * NT + t) * NA + (tid - 64)];
  __syncthreads();
  int g = tid >> 2, jc = tid & 3;
  float Lg = Ls[g];
  us8 hv0, hv1, lv0, lv1;
#pragma unroll
  for (int k = 0; k < 8; ++k) {
    unsigned short hs, ls;
    split_hl(Lg * uu[jc * 16 + k], hs, ls);
    hv0[k] = hs; lv0[k] = ls;
  }
#pragma unroll
  for (int k = 0; k < 8; ++k) {
    unsigned short hs, ls;
    split_hl(Lg * uu[jc * 16 + 8 + k], hs, ls);
    hv1[k] = hs; lv1[k] = ls;
  }
  size_t ob = ((size_t)(g >> 2) * (NT * NB) + tb) * 256 + (g & 3) * 64 + jc * 16;
  *(us8*)(Uph + ob) = hv0; *(us8*)(Uph + ob + 8) = hv1;
  *(us8*)(Upl + ob) = lv0; *(us8*)(Upl + ob + 8) = lv1;
}

// x0 -> packed hi|lo state
__global__ void k_x0(const float* __restrict__ x0, unsigned* __restrict__ Xst) {
  int idx = blockIdx.x * 256 + threadIdx.x;
  float x = x0[idx];
  half_t hi = (half_t)x;
  half_t lo = (half_t)((x - (float)hi) * LO_SCALE);
  union { half_t h[2]; unsigned u; } P;
  P.h[0] = hi; P.h[1] = lo;
  Xst[idx] = P.u;
}

// Bu GEMM: partials P[ks][tb][i] (plain stores, NO atomics); Ksplit=16.
__launch_bounds__(256, 4)
__global__ void k_bu2(const unsigned short* __restrict__ Uph,
                      const unsigned short* __restrict__ Upl,
                      const unsigned short* __restrict__ MBTh,
                      const unsigned short* __restrict__ MBTl,
                      float* __restrict__ V, float* Pbu) {
  const int tid = threadIdx.x;
  const int wv = tid >> 6, lane = tid & 63;
  const int l15 = lane & 15, quad = lane >> 4;
  const int mt = blockIdx.x >> 4, ks = blockIdx.x & 15;
  const int r0 = mt * 64 + wv * 16;
  half8 ah[8], al[8];
  const size_t ab = ((size_t)ks * (NT * NB) + r0 + l15) * 256 + quad * 8;
#pragma unroll
  for (int k8 = 0; k8 < 8; ++k8) {
    ah[k8] = *(const half8*)(Uph + ab + k8 * 32);
    al[k8] = *(const half8*)(Upl + ab + k8 * 32);
  }
  for (int cg = 0; cg < 4; ++cg) {
    float4v accA[4], accC[4];
#pragma unroll
    for (int c = 0; c < 4; ++c) {
      accA[c] = (float4v){0.f, 0.f, 0.f, 0.f};
      accC[c] = (float4v){0.f, 0.f, 0.f, 0.f};
    }
#pragma unroll
    for (int c = 0; c < 4; ++c) {
      const int cf = cg * 4 + c;
      const size_t bb = ((size_t)ks * NS + cf * 16 + l15) * 256 + quad * 8;
#pragma unroll
      for (int k8 = 0; k8 < 8; ++k8) {
        half8 bh = *(const half8*)(MBTh + bb + k8 * 32);
        half8 bl = *(const half8*)(MBTl + bb + k8 * 32);
        accA[c] = __builtin_amdgcn_mfma_f32_16x16x32_f16(ah[k8], bh, accA[c], 0, 0, 0);
        accC[c] = __builtin_amdgcn_mfma_f32_16x16x32_f16(ah[k8], bl, accC[c], 0, 0, 0);
        accC[c] = __builtin_amdgcn_mfma_f32_16x16x32_f16(al[k8], bh, accC[c], 0, 0, 0);
      }
    }
#pragma unroll
    for (int c = 0; c < 4; ++c) {
      const int cf = cg * 4 + c;
#pragma unroll
      for (int r = 0; r < 4; ++r) {
        const int row = r0 + quad * 4 + r;
        const float v = accA[c][r] + accC[c][r] * LO_INV;
        if (Pbu) Pbu[((size_t)ks * (NT * NB) + row) * 256 + cf * 16 + l15] = v;
        else atomicAdd(V + (size_t)row * NS + cf * 16 + l15, v);
      }
    }
  }
}

// V[row][col] += sum_ks Pbu[ks][row][col]
__global__ void k_bur(const float* __restrict__ Pbu, float* __restrict__ V) {
  const int row = blockIdx.x, col = threadIdx.x;
  const size_t off = (size_t)row * 256 + col;
  float s = 0.f;
#pragma unroll
  for (int ks = 0; ks < 16; ++ks)
    s += Pbu[(size_t)ks * (NT * NB * 256) + off];
  V[off] += s;
}

// ---------------- fused pipeline kernel (1024 thr, 1 block/CU) ----------------
// blocks [0, nroll): rollout chains (16 waves, thread = (i, j-quarter)).
// blocks [nroll, nroll+192): pre role = 64 col-blocks x 3 row-thirds,
//   thread-per-column; L rows read as wave-uniform scalar loads (no LDS).
__launch_bounds__(1024, 4)
__global__ void k_pr(const unsigned short* Arh, const unsigned short* Arl,
                     unsigned short* Awh, unsigned short* Awl,
                     const float* __restrict__ Lf,
                     const float* __restrict__ MGf,
                     const float* __restrict__ b2a, const float* __restrict__ V,
                     unsigned* __restrict__ Xst, float* __restrict__ out,
                     int nroll, int t0r, int tnr, int t0p, int tnp) {
  __shared__ __align__(16) unsigned short xb[1024];   // 2 KiB (roll role only)
  const int tid = threadIdx.x;
  const int bid = blockIdx.x;

  if (bid < nroll) {
    // ===== rollout role =====
    __builtin_amdgcn_s_setprio(1);
    const int b = bid;
    const int i = tid >> 2, jq = tid & 3;
    if (tid < 256) {
      unsigned pxx = Xst[b * 256 + tid];
      xb[tid] = (unsigned short)(pxx & 0xffffu);
      xb[512 + tid] = (unsigned short)(pxx >> 16);
    }
    __syncthreads();
    int cur = 0;
    for (int tt = 0; tt < tnr; ++tt) {
      const int t = t0r + tt;
      const size_t ro = ((size_t)tt * NB + b) * (NS * NS) + (size_t)i * NS + jq * 64;
      const unsigned short* xhp = xb + cur * 256 + jq * 64;
      const unsigned short* xlp = xb + 512 + cur * 256 + jq * 64;
      float s1 = 0.f, s2 = 0.f;
#pragma unroll
      for (int q = 0; q < 8; ++q) {
        uint4v a4 = *(const uint4v*)(Arh + ro + q * 8);
        uint4v c4 = *(const uint4v*)(Arl + ro + q * 8);
        uint4v xh4 = *(const uint4v*)(xhp + q * 8);
        uint4v xl4 = *(const uint4v*)(xlp + q * 8);
#pragma unroll
        for (int p = 0; p < 4; ++p) {
          s1 = fdot2f(as_h2(a4[p]), as_h2(xh4[p]), s1);
          s2 = fdot2f(as_h2(a4[p]), as_h2(xl4[p]), s2);
          s2 = fdot2f(as_h2(c4[p]), as_h2(xh4[p]), s2);
        }
      }
      float d = s1 + s2 * LO_INV;
      d += __shfl_xor(d, 1);
      d += __shfl_xor(d, 2);
      if (jq == 0) {
        float xn = d + V[((size_t)t * NB + b) * NS + i];
        out[((size_t)b * NT + t) * NS + i] = xn;
        unsigned short hs, ls;
        split_hl(xn, hs, ls);
        xb[(cur ^ 1) * 256 + i] = hs;
        xb[512 + (cur ^ 1) * 256 + i] = ls;
      }
      __syncthreads();
      cur ^= 1;
    }
    if (tid < 256) {
      unsigned pxx = (unsigned)xb[cur * 256 + tid] |
                     ((unsigned)xb[512 + cur * 256 + tid] << 16);
      Xst[b * 256 + tid] = pxx;
    }
    __builtin_amdgcn_s_setprio(0);
  } else {
    // ===== pre role: direct f32 VALU A-materialization (next chunk) =====
    const int pb = bid - nroll;          // 0..191
    const int cbk = pb / 3, rth = pb % 3;
    const int m = cbk * 1024 + tid;      // this thread's output column
    const int R = tnp * NB;              // chunk rows (<=320)
    const int per = (R + 2) / 3;
    const int r0 = rth * per;
    const int r1 = (r0 + per < R) ? (r0 + per) : R;
    float2v mg2[32];
#pragma unroll
    for (int g2 = 0; g2 < 32; ++g2) {
      mg2[g2][0] = MGf[(size_t)(g2 * 2) * (NS * NS) + m];
      mg2[g2][1] = MGf[(size_t)(g2 * 2 + 1) * (NS * NS) + m];
    }
    const float b2v = b2a[m];
    for (int r = r0; r < r1; ++r) {
      // wave-uniform row pointer -> scalar loads on the SMEM pipe
      const float* __restrict__ Lr = Lf + ((size_t)(t0p * NB) + r) * NG;
      float2v a2 = {0.f, 0.f};
#pragma unroll
      for (int g2 = 0; g2 < 32; ++g2) {
        float2v l2 = {Lr[g2 * 2], Lr[g2 * 2 + 1]};
        a2 += l2 * mg2[g2];
      }
      float v = a2[0] + a2[1] + b2v;
      unsigned short hs, ls;
      split_hl(v, hs, ls);
      const size_t gb = (size_t)r * (NS * NS) + m;
      Awh[gb] = hs;
      Awl[gb] = ls;
    }
  }
}

// ---------------- launch ----------------

static inline int imin(int a, int b) { return a < b ? a : b; }

extern "C" void kernel_launch(void* const* d_in, const int* in_sizes, int n_in,
                              void* d_out, int out_size, void* d_ws, size_t ws_size,
                              hipStream_t stream) {
  const float* x0  = (const float*)d_in[0];
  const float* ctx = (const float*)d_in[1];
  const float* usin = (const float*)d_in[2];
  const float* W1a = (const float*)d_in[3];
  const float* b1a = (const float*)d_in[4];
  const float* W2a = (const float*)d_in[5];
  const float* b2a = (const float*)d_in[6];
  const float* W1b = (const float*)d_in[7];
  const float* b1b = (const float*)d_in[8];
  const float* W2b = (const float*)d_in[9];
  const float* b2b = (const float*)d_in[10];
  float* out = (float*)d_out;

  const size_t perT  = (size_t)NB * NS * NS * 2;     //  8,388,608 per t per array
  const size_t szMGf = (size_t)NS * NS * NG * 4;     // 16,777,216
  const size_t szMBT = (size_t)NS * NG * NA * 2;     //  2,097,152 each
  const size_t szLf  = (size_t)NT * NB * NG * 4;     //    819,200
  const size_t szGt  = (size_t)NH * NG * 4;          //     65,536 each
  const size_t szUp1 = (size_t)NT * NB * NG * NA * 2;// 26,214,400 each
  const size_t szV   = (size_t)NT * NB * NS * 4;     //  3,276,800
  const size_t szXst = (size_t)NB * NS * 4;          //     65,536
  const size_t szPp  = (size_t)NG * NS * NS * 4 * 4; // 67,108,864 (aliases A0)
  const size_t szPb  = (size_t)NG * NS * NA * 4 * 4; // 16,777,216 (aliases A0 tail)
  const size_t szPbu = (size_t)16 * NT * NB * 256 * 4; // 52,428,800 (aliases A1)

  const size_t fixed = szMGf + 2 * szMBT + szLf + 2 * szGt + 2 * szUp1 + szV + szXst;

  size_t avail = (ws_size > fixed) ? (ws_size - fixed) : 0;
  bool dbuf = true;
  int Tc = (int)(avail / (4 * perT));
  if (Tc > 5) Tc = 5;
  if (Tc < 1) {
    dbuf = false;
    Tc = (int)(avail / (2 * perT));
    if (Tc > 5) Tc = 5;
    if (Tc < 1) Tc = 1;
  }

  char* p = (char*)d_ws;
  unsigned short* A0h = (unsigned short*)p; p += (size_t)Tc * perT;
  unsigned short* A0l = (unsigned short*)p; p += (size_t)Tc * perT;
  unsigned short* A1h = A0h; unsigned short* A1l = A0l;
  if (dbuf) {
    A1h = (unsigned short*)p; p += (size_t)Tc * perT;
    A1l = (unsigned short*)p; p += (size_t)Tc * perT;
  }
  float* MGf = (float*)p; p += szMGf;
  unsigned short* MBTh = (unsigned short*)p; p += szMBT;
  unsigned short* MBTl = (unsigned short*)p; p += szMBT;
  float* Lf  = (float*)p; p += szLf;
  float* Gt  = (float*)p; p += szGt;
  float* Gbt = (float*)p; p += szGt;
  unsigned short* Uph = (unsigned short*)p; p += szUp1;
  unsigned short* Upl = (unsigned short*)p; p += szUp1;
  float* Vg  = (float*)p; p += szV;
  unsigned* Xst = (unsigned*)p;

  // scratch aliasing (all uses strictly before the first k_pr launch):
  const bool fast_red = (2 * (size_t)Tc * perT) >= (szPp + szPb);
  float* Pp = (float*)A0h;
  float* Pb = Pp + szPp / 4;
  const bool part_bu = dbuf && (2 * (size_t)Tc * perT) >= szPbu;
  float* Pbu = part_bu ? (float*)A1h : nullptr;

  k_g<<<NG, NH, 0, stream>>>(W1a, b1a, W1b, b1b, Gt, Gbt);
  k_lag<<<(NT * NB + 255) / 256, 256, 0, stream>>>(ctx, Lf);
  k_v<<<NT * NB, NS, 0, stream>>>(b2b, usin, Vg);
  if (fast_red) {
    k_mg1<<<1024, 256, 0, stream>>>(W2a, Gt, Pp);
    k_mg2<<<(NG * NS * NS) / 1024, 256, 0, stream>>>(Pp, MGf);
    k_mb1<<<256, 256, 0, stream>>>(W2b, Gbt, Pb);
    k_mb2<<<64 * 64, 256, 0, stream>>>(Pb, MBTh, MBTl);
  } else {
    k_mgS<<<NS * NS / 256, 256, 0, stream>>>(W2a, Gt, MGf);
    k_mbS<<<NS * NA / 256, 256, 0, stream>>>(W2b, Gbt, MBTh, MBTl);
  }
  k_up<<<NT * NB, 256, 0, stream>>>(Lf, usin, Uph, Upl);
  k_x0<<<NB, 256, 0, stream>>>(x0, Xst);
  k_bu2<<<(NT * NB / 64) * 16, 256, 0, stream>>>(Uph, Upl, MBTh, MBTl, Vg, Pbu);
  if (part_bu) k_bur<<<NT * NB, 256, 0, stream>>>(Pbu, Vg);

  (void)in_sizes; (void)n_in; (void)out_size;

  const int nc = (NT + Tc - 1) / Tc;
  if (dbuf) {
    // pipelined: launch L runs roll(chunk L-1) || pre(chunk L); 64+192=256 blocks
    for (int L = 0; L <= nc; ++L) {
      const int rc = L - 1, pc = L;
      const int nroll = (rc >= 0) ? NB : 0;
      const int t0r = (rc >= 0) ? rc * Tc : 0;
      const int tnr = (rc >= 0) ? imin(Tc, NT - t0r) : 0;
      const int t0p = (pc < nc) ? pc * Tc : 0;
      const int tnp = (pc < nc) ? imin(Tc, NT - t0p) : 0;
      const int grid = nroll + (tnp > 0 ? 192 : 0);
      const unsigned short* Arh = ((rc & 1) ? A1h : A0h);
      const unsigned short* Arl = ((rc & 1) ? A1l : A0l);
      unsigned short* Awh = ((pc & 1) ? A1h : A0h);
      unsigned short* Awl = ((pc & 1) ? A1l : A0l);
      k_pr<<<grid, 1024, 0, stream>>>(Arh, Arl, Awh, Awl, Lf, MGf,
                                      b2a, Vg, Xst, out, nroll, t0r, tnr, t0p, tnp);
    }
  } else {
    // sequential fallback on a single buffer
    for (int c = 0; c < nc; ++c) {
      const int t0 = c * Tc, tn = imin(Tc, NT - t0);
      k_pr<<<192, 1024, 0, stream>>>(A0h, A0l, A0h, A0l, Lf, MGf,
                                     b2a, Vg, Xst, out, 0, 0, 0, t0, tn);
      k_pr<<<NB, 1024, 0, stream>>>(A0h, A0l, A0h, A0l, Lf, MGf,
                                    b2a, Vg, Xst, out, NB, t0, tn, 0, 0);
    }
  }
}